// Round 1
// 1354.514 us; speedup vs baseline: 1.4879x; 1.4879x over previous
//
#include <hip/hip_runtime.h>
#include <stdint.h>

// BiDense via i8 MFMA: y = bx*bkq*(4*P - 2*Sx - 2*Sk + K) + bias
// P = sum a'b' with a',b' in {0,1} (sign bits), computed by v_mfma_i32_32x32x32_i8.
// Bits stay packed in ws (13 MiB); expansion bits->0/1 bytes happens at LDS staging.

#define M_ROWS 8192      // B*S
#define D_DIM  4096      // K
#define F_DIM  16384     // N
#define KW     128       // D_DIM/32 words of sign bits per row
#define F32_EPS 1.1920928955078125e-7f

typedef int v4i  __attribute__((ext_vector_type(4)));
typedef int v16i __attribute__((ext_vector_type(16)));

// ---------------- pass 1a: pack x signs + row maxabs + row positive-count ----
__global__ __launch_bounds__(256) void pack_x(const float* __restrict__ x,
                                              uint32_t* __restrict__ xbits,
                                              float2* __restrict__ bxs) {
    const int row  = blockIdx.x;
    const int tid  = threadIdx.x;
    const int lane = tid & 63;
    const int wv   = tid >> 6;
    const float* xr = x + (size_t)row * D_DIM;
    float mv = 0.f;
    int   pc = 0;
#pragma unroll
    for (int it = 0; it < 16; ++it) {
        float v = xr[it * 256 + tid];
        mv = fmaxf(mv, fabsf(v));
        unsigned long long m = __ballot(v >= 0.f);
        if (lane == 0) {
            pc += __popcll(m);
            uint2 wp = make_uint2((uint32_t)m, (uint32_t)(m >> 32));
            *(uint2*)&xbits[(size_t)row * KW + 2 * (it * 4 + wv)] = wp;
        }
    }
#pragma unroll
    for (int off = 32; off > 0; off >>= 1)
        mv = fmaxf(mv, __shfl_down(mv, off, 64));
    __shared__ float sm[4];
    __shared__ int   sp[4];
    if (lane == 0) { sm[wv] = mv; sp[wv] = pc; }
    __syncthreads();
    if (tid == 0) {
        float m4 = fmaxf(fmaxf(sm[0], sm[1]), fmaxf(sm[2], sm[3]));
        int   s  = sp[0] + sp[1] + sp[2] + sp[3];
        // .x = bound (max|x|+eps), .y = K - 2*Sx  (exact in fp32)
        bxs[row] = make_float2(m4 + F32_EPS, (float)(D_DIM - 2 * s));
    }
}

// ---------------- pass 1b: pack kernel signs (per column f) + partial maxabs ----
// grid (64, 8): x -> 256-col group, y -> 512-row (d) segment
__global__ __launch_bounds__(256) void pack_k(const float* __restrict__ kern,
                                              uint32_t* __restrict__ kbits,
                                              float* __restrict__ bkpart) {
    const int f   = blockIdx.x * 256 + threadIdx.x;
    const int seg = blockIdx.y;
    const int d0  = seg * 512;
    const float* kp = kern + (size_t)d0 * F_DIM + f;
    float mv = 0.f;
#pragma unroll 1
    for (int wq = 0; wq < 16; wq += 4) {
        uint32_t w4[4];
#pragma unroll
        for (int q = 0; q < 4; ++q) {
            uint32_t wrd = 0;
#pragma unroll
            for (int b = 0; b < 32; ++b) {
                float v = kp[(size_t)((wq + q) * 32 + b) * F_DIM];
                mv = fmaxf(mv, fabsf(v));
                wrd |= (v >= 0.f ? 1u : 0u) << b;
            }
            w4[q] = wrd;
        }
        *(uint4*)&kbits[(size_t)f * KW + seg * 16 + wq] =
            make_uint4(w4[0], w4[1], w4[2], w4[3]);
    }
    bkpart[seg * F_DIM + f] = mv;
}

// ---------------- pass 1c: reduce maxabs + popcount column bits ----------------
__global__ __launch_bounds__(256) void reduce_bk(const float* __restrict__ bkpart,
                                                 const uint32_t* __restrict__ kbits,
                                                 float2* __restrict__ bks) {
    const int f = blockIdx.x * 256 + threadIdx.x;
    float m = 0.f;
#pragma unroll
    for (int seg = 0; seg < 8; ++seg)
        m = fmaxf(m, bkpart[seg * F_DIM + f]);
    int cnt = 0;
    const uint4* kr = (const uint4*)&kbits[(size_t)f * KW];
#pragma unroll
    for (int q = 0; q < 32; ++q) {
        uint4 v = kr[q];
        cnt += __popc(v.x) + __popc(v.y) + __popc(v.z) + __popc(v.w);
    }
    // .x = 0.25*(max+eps), .y = 2*Sk (exact in fp32)
    bks[f] = make_float2(0.25f * (m + F32_EPS), (float)(2 * cnt));
}

// ---------------- pass 2: i8 MFMA GEMM on 0/1 sign bytes ----------------
// block 256 thr (4 waves as 2x2), tile BM=128 x BN=256, BK=128 i8 per iter.
// wave tile 64x128 -> 2x4 MFMAs of 32x32x32_i8, acc = 8*16 = 128 VGPRs.
// LDS: A 128x128 i8 (16K) + B 256x128 i8 (32K), XOR-swizzle (row&7)<<4 on byte col.
#define BM  128
#define BN  256
#define BKB 128
#define NIT (D_DIM / BKB)   // 32
#define SWZ(r, c) ((c) ^ (((r) & 7) << 4))

__device__ __forceinline__ uint4 expand16(uint32_t w, int sh) {
    // bits [sh, sh+16) of w -> 16 bytes in {0,1} (4 dwords, little-endian = k-order)
    uint4 r;
    r.x = (((w >> (sh +  0)) & 0xFu) * 0x00204081u) & 0x01010101u;
    r.y = (((w >> (sh +  4)) & 0xFu) * 0x00204081u) & 0x01010101u;
    r.z = (((w >> (sh +  8)) & 0xFu) * 0x00204081u) & 0x01010101u;
    r.w = (((w >> (sh + 12)) & 0xFu) * 0x00204081u) & 0x01010101u;
    return r;
}

__global__ __launch_bounds__(256, 2) void bgemm(const uint32_t* __restrict__ xbits,
                                                const uint32_t* __restrict__ kbits,
                                                const float2* __restrict__ bxs,
                                                const float2* __restrict__ bks,
                                                const float* __restrict__ bias,
                                                float* __restrict__ out) {
    __shared__ uint4 xs4[BM * BKB / 16];
    __shared__ uint4 ks4[BN * BKB / 16];
    uint8_t* xs = (uint8_t*)xs4;
    uint8_t* ks = (uint8_t*)ks4;

    const int tid = threadIdx.x;
    const int m0 = blockIdx.y * BM;
    const int n0 = blockIdx.x * BN;

    // staging assignment: A: 2 words/thread (half row), B: 4 words/thread (full row)
    const int arow = tid >> 1;
    const int acb0 = (tid & 1) * 64;
    const uint32_t* gA = xbits + (size_t)(m0 + arow) * KW + (tid & 1) * 2;
    const uint32_t* gB = kbits + (size_t)(n0 + tid) * KW;
    uint2 ra = *(const uint2*)gA;
    uint4 rb = *(const uint4*)gB;

    // compute-side lane geometry
    const int lane = tid & 63;
    const int lo   = lane & 31;
    const int hi   = lane >> 5;
    const int wv   = tid >> 6;
    const int wm   = wv >> 1;              // 0..1 : 64-row slab
    const int wn   = wv & 1;               // 0..1 : 128-col slab
    const int arow0 = wm * 64 + lo;        // + i*32
    const int brow0 = wn * 128 + lo;       // + j*32
    const int swz   = (lo & 7) << 4;
    const int cshi  = hi * 16;

    v16i acc[2][4] = {};

    for (int it = 0; it < NIT; ++it) {
        // ---- stage: expand current bit regs into swizzled LDS ----
        {
            uint8_t* xd = xs + arow * BKB;
            *(uint4*)&xd[SWZ(arow, acb0 +  0)] = expand16(ra.x,  0);
            *(uint4*)&xd[SWZ(arow, acb0 + 16)] = expand16(ra.x, 16);
            *(uint4*)&xd[SWZ(arow, acb0 + 32)] = expand16(ra.y,  0);
            *(uint4*)&xd[SWZ(arow, acb0 + 48)] = expand16(ra.y, 16);
            uint8_t* kd = ks + tid * BKB;
            *(uint4*)&kd[SWZ(tid,   0)] = expand16(rb.x,  0);
            *(uint4*)&kd[SWZ(tid,  16)] = expand16(rb.x, 16);
            *(uint4*)&kd[SWZ(tid,  32)] = expand16(rb.y,  0);
            *(uint4*)&kd[SWZ(tid,  48)] = expand16(rb.y, 16);
            *(uint4*)&kd[SWZ(tid,  64)] = expand16(rb.z,  0);
            *(uint4*)&kd[SWZ(tid,  80)] = expand16(rb.z, 16);
            *(uint4*)&kd[SWZ(tid,  96)] = expand16(rb.w,  0);
            *(uint4*)&kd[SWZ(tid, 112)] = expand16(rb.w, 16);
        }
        // prefetch next iter's bits (lands during compute)
        if (it + 1 < NIT) {
            gA += 4; gB += 4;
            ra = *(const uint2*)gA;
            rb = *(const uint4*)gB;
        }
        __syncthreads();

        // ---- compute: 4 K-steps of 32, 2x4 MFMAs each ----
#pragma unroll
        for (int kst = 0; kst < 4; ++kst) {
            const int cb = ((kst * 32) | cshi) ^ swz;
            v4i a[2], b[4];
#pragma unroll
            for (int i = 0; i < 2; ++i)
                a[i] = *(const v4i*)(xs + (arow0 + i * 32) * BKB + cb);
#pragma unroll
            for (int j = 0; j < 4; ++j)
                b[j] = *(const v4i*)(ks + (brow0 + j * 32) * BKB + cb);
#pragma unroll
            for (int i = 0; i < 2; ++i)
#pragma unroll
                for (int j = 0; j < 4; ++j)
                    acc[i][j] = __builtin_amdgcn_mfma_i32_32x32x32_i8(
                        a[i], b[j], acc[i][j], 0, 0, 0);
        }
        __syncthreads();
    }

    // ---- epilogue: y = bx * bkq * (4P + (K-2Sx) - 2Sk) + bias ----
    const int colb = n0 + wn * 128 + lo;           // + j*32
    float2 bkv[4]; float bz[4];
#pragma unroll
    for (int j = 0; j < 4; ++j) {
        bkv[j] = bks[colb + j * 32];
        bz[j]  = bias[colb + j * 32];
    }
    const int rowb = m0 + wm * 64 + 4 * hi;
#pragma unroll
    for (int i = 0; i < 2; ++i) {
#pragma unroll
        for (int rq = 0; rq < 4; ++rq) {
#pragma unroll
            for (int rr = 0; rr < 4; ++rr) {
                const int r   = rq * 4 + rr;
                const int row = rowb + i * 32 + 8 * rq + rr;
                const float2 bxv = bxs[row];
                float* orow = out + (size_t)row * F_DIM;
#pragma unroll
                for (int j = 0; j < 4; ++j) {
                    const float t = 4.f * (float)acc[i][j][r] + (bxv.y - bkv[j].y);
                    orow[colb + j * 32] = bxv.x * bkv[j].x * t + bz[j];
                }
            }
        }
    }
}

extern "C" void kernel_launch(void* const* d_in, const int* in_sizes, int n_in,
                              void* d_out, int out_size, void* d_ws, size_t ws_size,
                              hipStream_t stream) {
    const float* x    = (const float*)d_in[0];
    const float* kern = (const float*)d_in[1];
    const float* bias = (const float*)d_in[2];
    float* out = (float*)d_out;

    uint8_t* ws = (uint8_t*)d_ws;
    // ws layout (13.0 MiB total, within previously-proven envelope)
    uint32_t* xbits  = (uint32_t*)ws;                          // 4 MiB
    uint32_t* kbits  = (uint32_t*)(ws + 4194304);              // 8 MiB
    float2*   bxs    = (float2*)(ws + 12582912);               // 64 KiB
    float2*   bks    = (float2*)(ws + 12648448);               // 128 KiB
    float*    bkpart = (float*)(ws + 12779520);                // 512 KiB

    pack_x   <<<M_ROWS, 256, 0, stream>>>(x, xbits, bxs);
    pack_k   <<<dim3(64, 8), 256, 0, stream>>>(kern, kbits, bkpart);
    reduce_bk<<<64, 256, 0, stream>>>(bkpart, kbits, bks);
    bgemm    <<<dim3(F_DIM / BN, M_ROWS / BM), 256, 0, stream>>>(
                 xbits, kbits, bxs, bks, bias, out);
}

// Round 2
// 1230.820 us; speedup vs baseline: 1.6374x; 1.1005x over previous
//
#include <hip/hip_runtime.h>
#include <stdint.h>

// BiDense via i8 MFMA: y = bx*bkq*(4*P - 2*Sx - 2*Sk + K) + bias
// P = sum a'b', a',b' in {0,1} (sign bits), via v_mfma_i32_32x32x32_i8.
// Bits stored TILE-MAJOR: per (tile, k-iter) a contiguous 2KB chunk of 512 words,
// word w = (row&255)*2 + h  (h = 32-bit half of the 64-bit k-chunk).
// bgemm: 256x256 tile, BK=64, double-buffered LDS (64KB), 1 barrier/iter.

#define M_ROWS 8192
#define D_DIM  4096
#define F_DIM  16384
#define NKI    64            // k-iters of 64 bits
#define F32_EPS 1.1920928955078125e-7f

typedef int v4i  __attribute__((ext_vector_type(4)));
typedef int v16i __attribute__((ext_vector_type(16)));

// ---------------- pass 1a: pack x signs (tile-major) + row maxabs + popcount ----
__global__ __launch_bounds__(256) void pack_x(const float* __restrict__ x,
                                              uint32_t* __restrict__ xbits,
                                              float2* __restrict__ bxs) {
    const int row  = blockIdx.x;
    const int tid  = threadIdx.x;
    const int lane = tid & 63;
    const int wv   = tid >> 6;
    const float* xr = x + (size_t)row * D_DIM;
    uint32_t* xt = xbits + (size_t)(row >> 8) * (NKI * 512);
    float mv = 0.f;
    int   pc = 0;
#pragma unroll
    for (int it = 0; it < 16; ++it) {
        float v = xr[it * 256 + tid];
        mv = fmaxf(mv, fabsf(v));
        unsigned long long m = __ballot(v >= 0.f);
        if (lane == 0) {
            pc += __popcll(m);
            const int ki = it * 4 + wv;
            *(uint2*)&xt[(size_t)ki * 512 + (row & 255) * 2] =
                make_uint2((uint32_t)m, (uint32_t)(m >> 32));
        }
    }
#pragma unroll
    for (int off = 32; off > 0; off >>= 1)
        mv = fmaxf(mv, __shfl_down(mv, off, 64));
    __shared__ float sm[4];
    __shared__ int   sp[4];
    if (lane == 0) { sm[wv] = mv; sp[wv] = pc; }
    __syncthreads();
    if (tid == 0) {
        float m4 = fmaxf(fmaxf(sm[0], sm[1]), fmaxf(sm[2], sm[3]));
        int   s  = sp[0] + sp[1] + sp[2] + sp[3];
        bxs[row] = make_float2(m4 + F32_EPS, (float)(D_DIM - 2 * s));
    }
}

// ---------------- pass 1b: pack kernel signs, float4-coalesced ----------------
// grid (16, 32): x -> 1024 f-cols (4/thread), y -> 128 d-rows. atomicMax for bound.
__global__ __launch_bounds__(256) void pack_k(const float* __restrict__ kern,
                                              uint32_t* __restrict__ kbits,
                                              uint32_t* __restrict__ bkmax) {
    const int tid = threadIdx.x;
    const int f0  = blockIdx.x * 1024 + tid * 4;
    const int d0  = blockIdx.y * 128;
    const float* kp = kern + (size_t)d0 * F_DIM + f0;
    uint32_t w[4][4] = {{0}};    // [col][word]
    float mx[4] = {0.f, 0.f, 0.f, 0.f};
#pragma unroll 1
    for (int dw = 0; dw < 4; ++dw) {
#pragma unroll
        for (int b = 0; b < 32; ++b) {
            float4 v = *(const float4*)&kp[(size_t)(dw * 32 + b) * F_DIM];
            mx[0] = fmaxf(mx[0], fabsf(v.x)); w[0][dw] |= (v.x >= 0.f ? 1u : 0u) << b;
            mx[1] = fmaxf(mx[1], fabsf(v.y)); w[1][dw] |= (v.y >= 0.f ? 1u : 0u) << b;
            mx[2] = fmaxf(mx[2], fabsf(v.z)); w[2][dw] |= (v.z >= 0.f ? 1u : 0u) << b;
            mx[3] = fmaxf(mx[3], fabsf(v.w)); w[3][dw] |= (v.w >= 0.f ? 1u : 0u) << b;
        }
    }
    // 4 words = k-iters (by*2, by*2+1), halves h=0,1 each
    uint32_t* kt = kbits + (size_t)(f0 >> 8) * (NKI * 512)
                         + (size_t)(blockIdx.y * 2) * 512;
#pragma unroll
    for (int c = 0; c < 4; ++c) {
        const int fo = ((f0 + c) & 255) * 2;
        *(uint2*)&kt[fo]       = make_uint2(w[c][0], w[c][1]);
        *(uint2*)&kt[512 + fo] = make_uint2(w[c][2], w[c][3]);
        atomicMax(&bkmax[f0 + c], __float_as_uint(mx[c]));
    }
}

// ---------------- pass 1c: finalize bounds + column popcount ----------------
__global__ __launch_bounds__(256) void reduce_bk(const uint32_t* __restrict__ bkmax,
                                                 const uint32_t* __restrict__ kbits,
                                                 float2* __restrict__ bks) {
    const int f = blockIdx.x * 256 + threadIdx.x;
    const uint32_t* kt = kbits + (size_t)(f >> 8) * (NKI * 512) + (f & 255) * 2;
    int cnt = 0;
#pragma unroll
    for (int ki = 0; ki < NKI; ++ki) {
        uint2 v = *(const uint2*)&kt[(size_t)ki * 512];
        cnt += __popc(v.x) + __popc(v.y);
    }
    float m = __uint_as_float(bkmax[f]);
    bks[f] = make_float2(0.25f * (m + F32_EPS), (float)(2 * cnt));
}

// ---------------- pass 2: i8 MFMA GEMM, 256x256 tile, dbuf LDS ----------------
#define BM  256
#define BN  256
#define BKB 64               // i8 k per iter
#define NIT (D_DIM / BKB)    // 64
#define SWZ64(r, c) ((c) ^ ((((r) >> 1) & 3) << 4))

__device__ __forceinline__ uint4 expand16(uint32_t w, int sh) {
    // bits [sh, sh+16) of w -> 16 bytes in {0,1}, little-endian (k order)
    uint4 r;
    r.x = (((w >> (sh +  0)) & 0xFu) * 0x00204081u) & 0x01010101u;
    r.y = (((w >> (sh +  4)) & 0xFu) * 0x00204081u) & 0x01010101u;
    r.z = (((w >> (sh +  8)) & 0xFu) * 0x00204081u) & 0x01010101u;
    r.w = (((w >> (sh + 12)) & 0xFu) * 0x00204081u) & 0x01010101u;
    return r;
}

__global__ __launch_bounds__(512, 2) void bgemm(const uint32_t* __restrict__ xbits,
                                                const uint32_t* __restrict__ kbits,
                                                const float2* __restrict__ bxs,
                                                const float2* __restrict__ bks,
                                                const float* __restrict__ bias,
                                                float* __restrict__ out) {
    __shared__ uint4 xs4[2][BM * BKB / 16];   // 2 x 16KB
    __shared__ uint4 ks4[2][BN * BKB / 16];   // 2 x 16KB

    const int tid = threadIdx.x;
    const int m0 = blockIdx.y * BM;
    const int n0 = blockIdx.x * BN;

    const uint32_t* gA = xbits + (size_t)blockIdx.y * (NKI * 512) + tid;
    const uint32_t* gB = kbits + (size_t)blockIdx.x * (NKI * 512) + tid;

    // staging geometry: word tid -> row tid>>1, half tid&1
    const int srow = tid >> 1;
    const int sc0  = (tid & 1) * 32;

    // compute geometry: 8 waves as 2(m) x 4(n); wave tile 128x64
    const int lane = tid & 63;
    const int lo   = lane & 31;
    const int hi   = lane >> 5;
    const int wv   = tid >> 6;
    const int wm   = wv >> 2;
    const int wn   = wv & 3;
    const int swz  = ((lo >> 1) & 3) << 4;
    const int cshi = hi * 16;

    v16i acc[4][2] = {};

    uint32_t wa = gA[0], wb = gB[0];

    auto STAGE = [&](int buf, uint32_t A, uint32_t B) {
        uint8_t* xd = (uint8_t*)xs4[buf] + srow * BKB;
        *(uint4*)&xd[SWZ64(srow, sc0)]      = expand16(A, 0);
        *(uint4*)&xd[SWZ64(srow, sc0 + 16)] = expand16(A, 16);
        uint8_t* kd = (uint8_t*)ks4[buf] + srow * BKB;
        *(uint4*)&kd[SWZ64(srow, sc0)]      = expand16(B, 0);
        *(uint4*)&kd[SWZ64(srow, sc0 + 16)] = expand16(B, 16);
    };

    // prologue
    STAGE(0, wa, wb);
    wa = gA[512]; wb = gB[512];
    __syncthreads();

#pragma unroll 2
    for (int t = 0; t < NIT; ++t) {
        const int cur = t & 1;
        if (t + 1 < NIT) {
            STAGE(cur ^ 1, wa, wb);
            if (t + 2 < NIT) {
                wa = gA[(size_t)(t + 2) * 512];
                wb = gB[(size_t)(t + 2) * 512];
            }
        }
        const uint8_t* xb = (const uint8_t*)xs4[cur];
        const uint8_t* kb = (const uint8_t*)ks4[cur];
        __builtin_amdgcn_s_setprio(1);
#pragma unroll
        for (int kst = 0; kst < 2; ++kst) {
            const int cb = (kst * 32 + cshi) ^ swz;
            v4i a[4], b[2];
#pragma unroll
            for (int i = 0; i < 4; ++i)
                a[i] = *(const v4i*)(xb + (wm * 128 + lo + i * 32) * BKB + cb);
#pragma unroll
            for (int j = 0; j < 2; ++j)
                b[j] = *(const v4i*)(kb + (wn * 64 + lo + j * 32) * BKB + cb);
#pragma unroll
            for (int i = 0; i < 4; ++i)
#pragma unroll
                for (int j = 0; j < 2; ++j)
                    acc[i][j] = __builtin_amdgcn_mfma_i32_32x32x32_i8(
                        a[i], b[j], acc[i][j], 0, 0, 0);
        }
        __builtin_amdgcn_s_setprio(0);
        __syncthreads();
    }

    // epilogue: y = bx*bkq*(4P + (K-2Sx) - 2Sk) + bias
    const int colb = n0 + wn * 64 + lo;
    float2 bkv[2]; float bz[2];
#pragma unroll
    for (int j = 0; j < 2; ++j) {
        bkv[j] = bks[colb + j * 32];
        bz[j]  = bias[colb + j * 32];
    }
    const int rowb = m0 + wm * 128 + 4 * hi;
#pragma unroll
    for (int i = 0; i < 4; ++i) {
#pragma unroll
        for (int rq = 0; rq < 4; ++rq) {
#pragma unroll
            for (int rr = 0; rr < 4; ++rr) {
                const int r   = rq * 4 + rr;
                const int row = rowb + i * 32 + 8 * rq + rr;
                const float2 bxv = bxs[row];
                float* orow = out + (size_t)row * F_DIM;
#pragma unroll
                for (int j = 0; j < 2; ++j) {
                    const float tv = 4.f * (float)acc[i][j][r] + (bxv.y - bkv[j].y);
                    orow[colb + j * 32] = bxv.x * bkv[j].x * tv + bz[j];
                }
            }
        }
    }
}

extern "C" void kernel_launch(void* const* d_in, const int* in_sizes, int n_in,
                              void* d_out, int out_size, void* d_ws, size_t ws_size,
                              hipStream_t stream) {
    const float* x    = (const float*)d_in[0];
    const float* kern = (const float*)d_in[1];
    const float* bias = (const float*)d_in[2];
    float* out = (float*)d_out;

    uint8_t* ws = (uint8_t*)d_ws;
    // ws layout (12.25 MiB, within proven envelope)
    uint32_t* xbits = (uint32_t*)ws;                    // 4 MiB
    uint32_t* kbits = (uint32_t*)(ws + 4194304);        // 8 MiB
    float2*   bxs   = (float2*)(ws + 12582912);         // 64 KiB
    float2*   bks   = (float2*)(ws + 12648448);         // 128 KiB
    uint32_t* bkmax = (uint32_t*)(ws + 12779520);       // 64 KiB

    hipMemsetAsync(bkmax, 0, 65536, stream);
    pack_x   <<<M_ROWS, 256, 0, stream>>>(x, xbits, bxs);
    pack_k   <<<dim3(16, 32), 256, 0, stream>>>(kern, kbits, bkmax);
    reduce_bk<<<64, 256, 0, stream>>>(bkmax, kbits, bks);
    bgemm    <<<dim3(F_DIM / BN, M_ROWS / BM), 512, 0, stream>>>(
                 xbits, kbits, bxs, bks, bias, out);
}